// Round 11
// baseline (136.675 us; speedup 1.0000x reference)
//
#include <hip/hip_runtime.h>
#include <hip/hip_bf16.h>
#include <stdint.h>

#define BDIM 256

typedef __attribute__((ext_vector_type(8))) short short8;
typedef __attribute__((ext_vector_type(4))) float f32x4;

#define AS1 __attribute__((address_space(1)))
#define AS3 __attribute__((address_space(3)))
// async global->LDS DMA, 16B/lane; LDS dest must be wave-uniform base + lane*16 (m104/m108)
#define GLL16(g, s) __builtin_amdgcn_global_load_lds((AS1 const void*)(g), (AS3 void*)(s), 16, 0, 0)

__device__ __forceinline__ unsigned short f2bf(float f) {
  union { float f; unsigned u; } v; v.f = f;
  unsigned r = v.u + 0x7fffu + ((v.u >> 16) & 1u);  // round-to-nearest-even
  return (unsigned short)(r >> 16);
}
__device__ __forceinline__ float bf2f(unsigned short u) {
  union { unsigned u; float f; } v; v.u = ((unsigned)u) << 16;
  return v.f;
}

// counted vmcnt wait (T4) + sched_barrier pin (rule #18 discipline).
template <int N> __device__ __forceinline__ void vmwait() {
  static_assert(N >= 0 && N <= 8, "unsupported vmcnt");
  if constexpr (N == 8)      asm volatile("s_waitcnt vmcnt(8)" ::: "memory");
  else if constexpr (N == 7) asm volatile("s_waitcnt vmcnt(7)" ::: "memory");
  else if constexpr (N == 6) asm volatile("s_waitcnt vmcnt(6)" ::: "memory");
  else if constexpr (N == 5) asm volatile("s_waitcnt vmcnt(5)" ::: "memory");
  else if constexpr (N == 4) asm volatile("s_waitcnt vmcnt(4)" ::: "memory");
  else if constexpr (N == 3) asm volatile("s_waitcnt vmcnt(3)" ::: "memory");
  else if constexpr (N == 2) asm volatile("s_waitcnt vmcnt(2)" ::: "memory");
  else if constexpr (N == 1) asm volatile("s_waitcnt vmcnt(1)" ::: "memory");
  else                       asm volatile("s_waitcnt vmcnt(0)" ::: "memory");
  __builtin_amdgcn_sched_barrier(0);
}

// ---- weight conversion: W1 [1024,676] -> bf16 [1024,704] zero-padded K ----
__global__ __launch_bounds__(BDIM) void cast_pad_w1(const float* __restrict__ w,
                                                    unsigned short* __restrict__ o) {
  int idx = blockIdx.x * BDIM + threadIdx.x;
  if (idx >= 1024 * 704) return;
  int n = idx / 704, k = idx - n * 704;
  float v = (k < 676) ? w[n * 676 + k] : 0.f;
  o[idx] = f2bf(v);
}

__global__ __launch_bounds__(BDIM) void cast_plain(const float* __restrict__ w,
                                                   unsigned short* __restrict__ o, int count) {
  int idx = blockIdx.x * BDIM + threadIdx.x;
  if (idx < count) o[idx] = f2bf(w[idx]);
}

// ---- conv 3x3 VALID, 28x28 -> 26x26, f32 compute, bf16 out padded 676->704 ----
__global__ __launch_bounds__(BDIM) void conv3x3(const float* __restrict__ x,
                                                const float* __restrict__ cw,
                                                unsigned short* __restrict__ h0) {
  __shared__ float xs[784];
  __shared__ float w[9];
  int m = blockIdx.x;
  const float* xr = x + (size_t)m * 784;
  if (threadIdx.x < 9) w[threadIdx.x] = cw[threadIdx.x];
  for (int i = threadIdx.x; i < 784; i += BDIM) xs[i] = xr[i];
  __syncthreads();
  unsigned short* hr = h0 + (size_t)m * 704;
  for (int p = threadIdx.x; p < 704; p += BDIM) {
    float v = 0.f;
    if (p < 676) {
      int r = p / 26, c = p - r * 26;
      const float* xp = &xs[r * 28 + c];
      v = xp[0]  * w[0] + xp[1]  * w[1] + xp[2]  * w[2]
        + xp[28] * w[3] + xp[29] * w[4] + xp[30] * w[5]
        + xp[56] * w[6] + xp[57] * w[7] + xp[58] * w[8];
    }
    hr[p] = f2bf(v);
  }
}

// ---- B-DIRECT GEMM: C = act(A * Wt^T + bias) -> bf16 ----
// A [M,K] bf16 staged via gload_lds (DMA path); Wt [N,K] bf16 (the small,
// L2-resident weight panel) read DIRECTLY global->MFMA registers, one tile
// ahead, with NO barrier dependency (compiler auto-waits on register use;
// flight time = one full compute phase). Rationale: r4-r9 showed the
// barrier-synced DMA path caps at ~16 B/cyc/CU; B through VMEM-reg removes
// half the DMA bytes (r9 staged 890 MB; this stages 385 MB) and B's barrier.
// Geometry: 4 waves as COLUMNS (WGN=4, no B duplication): wave w owns cols
// [w*32, w*32+32), FM=BM/16 rows-frags, FN=BN/64 col-frags. BK=32.
// LDS = A only (2-buf 16 KB) + epilogue scratch; 3 blocks/CU.
//  * A swizzle key (row>>1)&3 [r9 fix: row&3 left 4-way conflicts at BK=32;
//    (row>>1)&3 gives 16 rows -> 8 bank-quads x 2-way = free, m136].
//  * LDS-transpose epilogue -> coalesced 16B stores (WRITE = ideal, r4).
// Loop: STAGE_A(t+1) -> issue B(t+1)->regs -> ds_read A(t) -> MFMA(t) with
// B(t) regs -> vmcnt(FN: A landed, B flying) -> s_barrier -> bc=bn.
template <int BM, int BN, bool RELU>
__global__ __launch_bounds__(BDIM, 3) void gemm_bd(const unsigned short* __restrict__ A,
                                                   const unsigned short* __restrict__ Wt,
                                                   const float* __restrict__ bias,
                                                   unsigned short* __restrict__ Cb,
                                                   int M, int N, int K) {
  constexpr int FM = BM / 16;         // M-fragments per wave (all waves same rows)
  constexpr int FN = BN / 64;         // N-fragments per wave (wave-column split)
  constexpr int RA = BM / 64;         // A staging rounds (1 GLL16/thread each)
  constexpr int LDSE = (2 * BM * 32 > BM * BN) ? 2 * BM * 32 : BM * BN;
  __shared__ unsigned short lds[LDSE];

  const int tid = threadIdx.x;
  const int lane = tid & 63;
  const int wid = tid >> 6;

  // ---- chunked XCD mapping: co-locate the bcol-sharers of each A-slab ----
  const int nbm = M / BM, nbc = N / BN;
  const int grid = nbm * nbc;          // multiple of 8 in all configs here
  const int cpx = grid >> 3;
  const int nid = ((int)blockIdx.x & 7) * cpx + ((int)blockIdx.x >> 3);
  const int brow = (nid / nbc) * BM;
  const int bcol = (nid % nbc) * BN;

  // A staging: round r covers rows [r*64, r*64+64); thread t -> row r*64+t/4,
  // source slot (t&3) ^ ((row>>1)&3)  [involution; same key on the read side].
  // LDS dest linear (t*16B) per gload_lds requirement (m104).
  const int srow = tid >> 2;
  const int sslot = (tid & 3) ^ ((srow >> 1) & 3);
  const unsigned short* gA = A + (size_t)(brow + srow) * K + sslot * 8;
  const int sdst = tid * 8;

#define STAGE_A(buf, kt)                                                      \
  do { _Pragma("unroll")                                                      \
    for (int r = 0; r < RA; ++r)                                              \
      GLL16(gA + (size_t)r * 64 * K + (size_t)(kt) * 32,                      \
            lds + (buf) * BM * 32 + r * 2048 + sdst);                         \
  } while (0)

  f32x4 acc[FM][FN] = {};
  const int fr = lane & 15;            // row within 16x16 fragment
  const int h = lane >> 4;             // k-subgroup 0..3 (8 elems each)
  const int fx = (fr >> 1) & 3;        // read-side swizzle key
  const int bbase = wid * (FN * 16);   // wave's col base within tile

  // B fragment source: Wt[(bcol + bbase + n*16 + fr)][kt*32 + h*8 ..+8)
  const unsigned short* gB = Wt + (size_t)(bcol + bbase + fr) * K + h * 8;

  const int nk = K >> 5;
  short8 bc[FN], bn[FN];
#define LOADB(dst, kt)                                                        \
  do { _Pragma("unroll")                                                      \
    for (int n = 0; n < FN; ++n)                                              \
      dst[n] = *(const short8*)(gB + (size_t)(n * 16) * K + (size_t)(kt) * 32); \
  } while (0)

  // prologue: A(0) staged, B(0) in regs, drain once.
  STAGE_A(0, 0);
  LOADB(bc, 0);
  vmwait<0>();
  __builtin_amdgcn_s_barrier();
  __builtin_amdgcn_sched_barrier(0);

  int cur = 0;
  for (int kt = 0; kt < nk; ++kt) {
    if (kt + 1 < nk) {
      STAGE_A(cur ^ 1, kt + 1);        // DMA: A(t+1) -> alt buffer
      LOADB(bn, kt + 1);               // VMEM: B(t+1) -> regs (no barrier dep)
    }
    __builtin_amdgcn_sched_barrier(0); // keep issue-early
    const unsigned short* As0 = lds + cur * BM * 32;
    short8 af[FM];
#pragma unroll
    for (int m = 0; m < FM; ++m)
      af[m] = *(const short8*)&As0[(m * 16 + fr) * 32 + ((h ^ fx) << 3)];
    __builtin_amdgcn_s_setprio(1);     // T5
#pragma unroll
    for (int m = 0; m < FM; ++m)
#pragma unroll
      for (int n = 0; n < FN; ++n)
        acc[m][n] = __builtin_amdgcn_mfma_f32_16x16x32_bf16(af[m], bc[n], acc[m][n], 0, 0, 0);
    __builtin_amdgcn_s_setprio(0);
    __builtin_amdgcn_sched_barrier(0);
    // After the MFMA block, outstanding VMEM (newest->oldest) = B(t+1)'s FN
    // loads, then A(t+1)'s RA: vmcnt(FN) completes all of A(t+1), leaves
    // B(t+1) in flight (auto-waited at its register use next iteration).
    if (kt + 1 < nk) vmwait<FN>();
    else             vmwait<0>();      // tail: drain before epilogue LDS reuse
    __builtin_amdgcn_s_barrier();      // all reads of cur done; cur^1 ready
    __builtin_amdgcn_sched_barrier(0);
#pragma unroll
    for (int n = 0; n < FN; ++n) bc[n] = bn[n];
    cur ^= 1;
  }
#undef STAGE_A
#undef LOADB

  // ---- epilogue: frags -> LDS scratch (swizzled) -> coalesced 16B stores ----
  unsigned short* const scr = lds;     // BM*BN elems, fits LDSE by definition
  const int lrow0 = h << 2;            // wave rows = all of [0,BM)
  const int lcol0 = bbase + fr;
#pragma unroll
  for (int n = 0; n < FN; ++n) {
    const int col = lcol0 + n * 16;
    const float bv = bias[bcol + col];
#pragma unroll
    for (int m = 0; m < FM; ++m) {
#pragma unroll
      for (int j = 0; j < 4; ++j) {
        const int row = lrow0 + m * 16 + j;
        float v = acc[m][n][j] + bv;
        if (RELU) v = v > 0.f ? v : 0.f;
        scr[(row * BN + col) ^ ((row & 12) << 2)] = f2bf(v);
      }
    }
  }
  __syncthreads();
  constexpr int CPR = BN / 8;          // 16B chunks per row
  constexpr int TOT = BM * CPR;
#pragma unroll 2
  for (int i = tid; i < TOT; i += BDIM) {
    const int row = i / CPR, c = i % CPR;
    const int cs = c ^ ((row & 12) >> 1);  // same XOR at chunk granularity
    short8 vv = *(const short8*)&scr[row * BN + cs * 8];
    *(short8*)(Cb + (size_t)(brow + row) * N + bcol + c * 8) = vv;
  }
}

// ---- final layer: out[m,n] = sum_k h3[m,k]*W4[n,k] + b4[n], N=10, K=256, f32 out ----
__global__ __launch_bounds__(BDIM) void fc10(const unsigned short* __restrict__ h3,
                                             const float* __restrict__ W4,
                                             const float* __restrict__ b4,
                                             float* __restrict__ out) {
  int lane = threadIdx.x & 63;
  int wid = threadIdx.x >> 6;
  int m = blockIdx.x * 4 + wid;
  const unsigned short* hr = h3 + (size_t)m * 256 + lane * 4;
  uint64_t hv = *(const uint64_t*)hr;
  float e0 = bf2f((unsigned short)hv), e1 = bf2f((unsigned short)(hv >> 16));
  float e2 = bf2f((unsigned short)(hv >> 32)), e3 = bf2f((unsigned short)(hv >> 48));
#pragma unroll
  for (int n = 0; n < 10; ++n) {
    const float4 wv = *(const float4*)(W4 + n * 256 + lane * 4);
    float s = e0 * wv.x + e1 * wv.y + e2 * wv.z + e3 * wv.w;
#pragma unroll
    for (int off = 32; off > 0; off >>= 1) s += __shfl_xor(s, off);
    if (lane == n) out[(size_t)m * 10 + n] = s + b4[n];
  }
}

extern "C" void kernel_launch(void* const* d_in, const int* in_sizes, int n_in,
                              void* d_out, int out_size, void* d_ws, size_t ws_size,
                              hipStream_t stream) {
  const float* x  = (const float*)d_in[0];
  const float* cw = (const float*)d_in[1];
  const float* W1 = (const float*)d_in[2];
  const float* b1 = (const float*)d_in[3];
  const float* W2 = (const float*)d_in[4];
  const float* b2 = (const float*)d_in[5];
  const float* W3 = (const float*)d_in[6];
  const float* b3 = (const float*)d_in[7];
  const float* W4 = (const float*)d_in[8];
  const float* b4 = (const float*)d_in[9];
  float* out = (float*)d_out;

  char* ws = (char*)d_ws;
  // h0 [16384,704] bf16 (23,068,672 B) — region reused for h2 [16384,512]
  // h1 [16384,1024] bf16 (33,554,432 B) — region reused for h3 [16384,256]
  unsigned short* h0  = (unsigned short*)(ws);
  unsigned short* h1  = (unsigned short*)(ws + 23068672);
  unsigned short* W1b = (unsigned short*)(ws + 23068672 + 33554432);
  unsigned short* W2b = W1b + 1024 * 704;
  unsigned short* W3b = W2b + 512 * 1024;
  unsigned short* h2  = h0;
  unsigned short* h3  = h1;

  cast_pad_w1<<<2816, BDIM, 0, stream>>>(W1, W1b);
  cast_plain<<<2048, BDIM, 0, stream>>>(W2, W2b, 512 * 1024);
  cast_plain<<<512, BDIM, 0, stream>>>(W3, W3b, 256 * 512);
  conv3x3<<<16384, BDIM, 0, stream>>>(x, cw, h0);

  // GEMM1: M=16384 N=1024 K=704 (22 K-tiles of 32). 128x128, grid 1024.
  // A-DMA 184 MB; B (W1b 1.4 MB, L2-resident) via reg-direct.
  gemm_bd<128, 128, true><<<(16384 / 128) * (1024 / 128), BDIM, 0, stream>>>(
      h0, W1b, b1, h1, 16384, 1024, 704);
  // GEMM2: M=16384 N=512 K=1024 (32 K-tiles). 128x128, grid 512. A-DMA 134 MB.
  gemm_bd<128, 128, true><<<(16384 / 128) * (512 / 128), BDIM, 0, stream>>>(
      h1, W2b, b2, h2, 16384, 512, 1024);
  // GEMM3: M=16384 N=256 K=512 (16 K-tiles). 128x64, grid 512. A-DMA 67 MB.
  gemm_bd<128, 64, true><<<(16384 / 128) * (256 / 64), BDIM, 0, stream>>>(
      h2, W3b, b3, h3, 16384, 256, 512);
  fc10<<<16384 / 4, BDIM, 0, stream>>>(h3, W4, b4, out);
}

// Round 12
// 119.496 us; speedup vs baseline: 1.1438x; 1.1438x over previous
//
#include <hip/hip_runtime.h>
#include <hip/hip_bf16.h>
#include <stdint.h>

#define BDIM 256

typedef __attribute__((ext_vector_type(8))) short short8;
typedef __attribute__((ext_vector_type(4))) float f32x4;

#define AS1 __attribute__((address_space(1)))
#define AS3 __attribute__((address_space(3)))
// async global->LDS DMA, 16B/lane; LDS dest must be wave-uniform base + lane*16 (m104/m108)
#define GLL16(g, s) __builtin_amdgcn_global_load_lds((AS1 const void*)(g), (AS3 void*)(s), 16, 0, 0)

__device__ __forceinline__ unsigned short f2bf(float f) {
  union { float f; unsigned u; } v; v.f = f;
  unsigned r = v.u + 0x7fffu + ((v.u >> 16) & 1u);  // round-to-nearest-even
  return (unsigned short)(r >> 16);
}
__device__ __forceinline__ float bf2f(unsigned short u) {
  union { unsigned u; float f; } v; v.u = ((unsigned)u) << 16;
  return v.f;
}

// ---- weight conversion: W1 [1024,676] -> bf16 [1024,704] zero-padded K ----
__global__ __launch_bounds__(BDIM) void cast_pad_w1(const float* __restrict__ w,
                                                    unsigned short* __restrict__ o) {
  int idx = blockIdx.x * BDIM + threadIdx.x;
  if (idx >= 1024 * 704) return;
  int n = idx / 704, k = idx - n * 704;
  float v = (k < 676) ? w[n * 676 + k] : 0.f;
  o[idx] = f2bf(v);
}

__global__ __launch_bounds__(BDIM) void cast_plain(const float* __restrict__ w,
                                                   unsigned short* __restrict__ o, int count) {
  int idx = blockIdx.x * BDIM + threadIdx.x;
  if (idx < count) o[idx] = f2bf(w[idx]);
}

// ---- conv 3x3 VALID, 28x28 -> 26x26, f32 compute, bf16 out padded 676->704 ----
__global__ __launch_bounds__(BDIM) void conv3x3(const float* __restrict__ x,
                                                const float* __restrict__ cw,
                                                unsigned short* __restrict__ h0) {
  __shared__ float xs[784];
  __shared__ float w[9];
  int m = blockIdx.x;
  const float* xr = x + (size_t)m * 784;
  if (threadIdx.x < 9) w[threadIdx.x] = cw[threadIdx.x];
  for (int i = threadIdx.x; i < 784; i += BDIM) xs[i] = xr[i];
  __syncthreads();
  unsigned short* hr = h0 + (size_t)m * 704;
  for (int p = threadIdx.x; p < 704; p += BDIM) {
    float v = 0.f;
    if (p < 676) {
      int r = p / 26, c = p - r * 26;
      const float* xp = &xs[r * 28 + c];
      v = xp[0]  * w[0] + xp[1]  * w[1] + xp[2]  * w[2]
        + xp[28] * w[3] + xp[29] * w[4] + xp[30] * w[5]
        + xp[56] * w[6] + xp[57] * w[7] + xp[58] * w[8];
    }
    hr[p] = f2bf(v);
  }
}

// ---- multi-chain GEMM, LINEAR staging source ----
// C[m,n] = act(sum_k A[m,k]*Wt[n,k] + bias[n]) -> bf16. BK=32, 4 waves,
// 4 blocks/CU. EXACT r9 structure with ONE change: the XOR source/read
// swizzle is REMOVED (linear source slots, linear ds_read).
// Theory (r11 forensics): our staging ran at 15 B/cyc/CU vs m97's
// back-computed 44 B/cyc with the same instruction+structure; the only
// structural difference is our PERMUTED per-lane source order (slot XOR),
// which plausibly breaks gload_lds request coalescing. Linear source
// restores ascending lane->address order. The reintroduced ~8-way ds_read
// conflicts are accepted: drain-structure timing is conflict-insensitive
// (m252; stage+barrier dominates the critical path).
//  * LDS-transpose epilogue kept -> coalesced 16B stores (WRITE ideal, r4).
//  * Chunked XCD mapping kept.
template <int BM, int BN, int WGM, bool RELU>
__global__ __launch_bounds__(BDIM, 4) void gemm_bt6(const unsigned short* __restrict__ A,
                                                    const unsigned short* __restrict__ Wt,
                                                    const float* __restrict__ bias,
                                                    unsigned short* __restrict__ Cb,
                                                    int M, int N, int K) {
  constexpr int WGN = 4 / WGM;
  constexpr int FM = BM / WGM / 16;   // M-fragments per wave
  constexpr int FN = BN / WGN / 16;   // N-fragments per wave
  constexpr int RA = BM / 64;         // 64-row staging rounds for A
  constexpr int RB = BN / 64;
  __shared__ unsigned short lds[2 * (BM + BN) * 32];
  unsigned short* const Asb = lds;                 // [2][BM*32]
  unsigned short* const Bsb = lds + 2 * BM * 32;   // [2][BN*32]

  const int tid = threadIdx.x;
  const int lane = tid & 63;
  const int wid = tid >> 6;

  // ---- chunked XCD mapping: XCD x gets grid/8 consecutive tiles ----
  const int nbm = M / BM, nbc = N / BN;
  const int grid = nbm * nbc;          // multiple of 8 in all configs here
  const int cpx = grid >> 3;
  const int nid = ((int)blockIdx.x & 7) * cpx + ((int)blockIdx.x >> 3);
  const int brow = (nid / nbc) * BM;
  const int bcol = (nid % nbc) * BN;

  // staging: round r covers tile rows [r*64, r*64+64). Thread t -> row
  // r*64 + t/4, byte slot (t&3)*16 -- LINEAR (lane l address = base + l*16,
  // strictly ascending). LDS dest linear (t*16B).
  const int srow = tid >> 2;
  const unsigned short* gA = A + (size_t)(brow + srow) * K + (tid & 3) * 8;
  const unsigned short* gB = Wt + (size_t)(bcol + srow) * K + (tid & 3) * 8;
  const int sdst = tid * 8;  // elements

#define STAGE(buf, kt)                                                        \
  do {                                                                        \
    _Pragma("unroll")                                                         \
    for (int r = 0; r < RA; ++r)                                              \
      GLL16(gA + (size_t)r * 64 * K + (size_t)(kt) * 32,                      \
            Asb + (buf) * BM * 32 + r * 2048 + sdst);                         \
    _Pragma("unroll")                                                         \
    for (int r = 0; r < RB; ++r)                                              \
      GLL16(gB + (size_t)r * 64 * K + (size_t)(kt) * 32,                      \
            Bsb + (buf) * BN * 32 + r * 2048 + sdst);                         \
  } while (0)

  f32x4 acc[FM][FN] = {};
  const int fr = lane & 15;            // row within 16x16 fragment
  const int h = lane >> 4;             // k-subgroup 0..3 (8 elems each)
  const int abase = (wid / WGN) * (FM * 16);
  const int bbase = (wid % WGN) * (FN * 16);
  const int slot = h << 3;             // LINEAR element offset within row

  const int nk = K >> 5;
  STAGE(0, 0);
  __syncthreads();
  int cur = 0;
  for (int kt = 0; kt < nk; ++kt) {
    if (kt + 1 < nk) STAGE(cur ^ 1, kt + 1);   // prefetch overlaps MFMA
    const unsigned short* As0 = Asb + cur * BM * 32;
    const unsigned short* Bs0 = Bsb + cur * BN * 32;
    short8 af[FM], bf[FN];
#pragma unroll
    for (int m = 0; m < FM; ++m)
      af[m] = *(const short8*)&As0[(abase + m * 16 + fr) * 32 + slot];
#pragma unroll
    for (int n = 0; n < FN; ++n)
      bf[n] = *(const short8*)&Bs0[(bbase + n * 16 + fr) * 32 + slot];
#pragma unroll
    for (int m = 0; m < FM; ++m)
#pragma unroll
      for (int n = 0; n < FN; ++n)
        acc[m][n] = __builtin_amdgcn_mfma_f32_16x16x32_bf16(af[m], bf[n], acc[m][n], 0, 0, 0);
    __syncthreads();                           // readers done + DMA drained
    cur ^= 1;
  }
#undef STAGE

  // ---- epilogue: frags -> LDS scratch (swizzled) -> coalesced 16B stores ----
  // scratch fits: BM*BN <= 2*(BM+BN)*32 for all configs used here.
  unsigned short* const scr = lds;
  const int lrow0 = abase + (h << 2);  // local row of j=0
  const int lcol0 = bbase + fr;
#pragma unroll
  for (int n = 0; n < FN; ++n) {
    const int col = lcol0 + n * 16;
    const float bv = bias[bcol + col];
#pragma unroll
    for (int m = 0; m < FM; ++m) {
#pragma unroll
      for (int j = 0; j < 4; ++j) {
        const int row = lrow0 + m * 16 + j;
        float v = acc[m][n][j] + bv;
        if (RELU) v = v > 0.f ? v : 0.f;
        scr[(row * BN + col) ^ ((row & 12) << 2)] = f2bf(v);
      }
    }
  }
  __syncthreads();
  constexpr int CPR = BN / 8;        // 16B chunks per row
  constexpr int TOT = BM * CPR;
#pragma unroll 2
  for (int i = tid; i < TOT; i += BDIM) {
    const int row = i / CPR, c = i % CPR;
    const int cs = c ^ ((row & 12) >> 1);     // same XOR at chunk granularity
    short8 vv = *(const short8*)&scr[row * BN + cs * 8];
    *(short8*)(Cb + (size_t)(brow + row) * N + bcol + c * 8) = vv;
  }
}

// ---- final layer: out[m,n] = sum_k h3[m,k]*W4[n,k] + b4[n], N=10, K=256, f32 out ----
__global__ __launch_bounds__(BDIM) void fc10(const unsigned short* __restrict__ h3,
                                             const float* __restrict__ W4,
                                             const float* __restrict__ b4,
                                             float* __restrict__ out) {
  int lane = threadIdx.x & 63;
  int wid = threadIdx.x >> 6;
  int m = blockIdx.x * 4 + wid;
  const unsigned short* hr = h3 + (size_t)m * 256 + lane * 4;
  uint64_t hv = *(const uint64_t*)hr;
  float e0 = bf2f((unsigned short)hv), e1 = bf2f((unsigned short)(hv >> 16));
  float e2 = bf2f((unsigned short)(hv >> 32)), e3 = bf2f((unsigned short)(hv >> 48));
#pragma unroll
  for (int n = 0; n < 10; ++n) {
    const float4 wv = *(const float4*)(W4 + n * 256 + lane * 4);
    float s = e0 * wv.x + e1 * wv.y + e2 * wv.z + e3 * wv.w;
#pragma unroll
    for (int off = 32; off > 0; off >>= 1) s += __shfl_xor(s, off);
    if (lane == n) out[(size_t)m * 10 + n] = s + b4[n];
  }
}

extern "C" void kernel_launch(void* const* d_in, const int* in_sizes, int n_in,
                              void* d_out, int out_size, void* d_ws, size_t ws_size,
                              hipStream_t stream) {
  const float* x  = (const float*)d_in[0];
  const float* cw = (const float*)d_in[1];
  const float* W1 = (const float*)d_in[2];
  const float* b1 = (const float*)d_in[3];
  const float* W2 = (const float*)d_in[4];
  const float* b2 = (const float*)d_in[5];
  const float* W3 = (const float*)d_in[6];
  const float* b3 = (const float*)d_in[7];
  const float* W4 = (const float*)d_in[8];
  const float* b4 = (const float*)d_in[9];
  float* out = (float*)d_out;

  char* ws = (char*)d_ws;
  // h0 [16384,704] bf16 (23,068,672 B) — region reused for h2 [16384,512]
  // h1 [16384,1024] bf16 (33,554,432 B) — region reused for h3 [16384,256]
  unsigned short* h0  = (unsigned short*)(ws);
  unsigned short* h1  = (unsigned short*)(ws + 23068672);
  unsigned short* W1b = (unsigned short*)(ws + 23068672 + 33554432);
  unsigned short* W2b = W1b + 1024 * 704;
  unsigned short* W3b = W2b + 512 * 1024;
  unsigned short* h2  = h0;
  unsigned short* h3  = h1;

  cast_pad_w1<<<2816, BDIM, 0, stream>>>(W1, W1b);
  cast_plain<<<2048, BDIM, 0, stream>>>(W2, W2b, 512 * 1024);
  cast_plain<<<512, BDIM, 0, stream>>>(W3, W3b, 256 * 512);
  conv3x3<<<16384, BDIM, 0, stream>>>(x, cw, h0);

  // GEMM1: M=16384 N=1024 K=704 (22 K-tiles of 32). 128x128, grid 1024 = 4/CU.
  gemm_bt6<128, 128, 2, true><<<(16384 / 128) * (1024 / 128), BDIM, 0, stream>>>(
      h0, W1b, b1, h1, 16384, 1024, 704);
  // GEMM2: M=16384 N=512 K=1024 (32 K-tiles). 128x128, grid 512 = 2/CU
  // (staged bytes 402 -> 262 MB vs r9's 64x128).
  gemm_bt6<128, 128, 2, true><<<(16384 / 128) * (512 / 128), BDIM, 0, stream>>>(
      h1, W2b, b2, h2, 16384, 512, 1024);
  // GEMM3: M=16384 N=256 K=512 (16 K-tiles). 128x64, grid 512 = 2/CU.
  gemm_bt6<128, 64, 2, true><<<(16384 / 128) * (256 / 64), BDIM, 0, stream>>>(
      h2, W3b, b3, h3, 16384, 256, 512);
  fc10<<<16384 / 4, BDIM, 0, stream>>>(h3, W4, b4, out);
}